// Round 1
// baseline (244.642 us; speedup 1.0000x reference)
//
#include <hip/hip_runtime.h>
#include <math.h>

#define Bz 8
#define Cc 12
#define Ss 784
#define Nn 785
#define Dd 768
#define Hh 28
#define K1 512
#define PATCHNUM 84

// ---------------- Kernel 1: per (b,c): top-84 select, new_score, flags ----------------
__global__ __launch_bounds__(256) void k1_score(const float* __restrict__ x,
                                                float* __restrict__ nscore,
                                                unsigned char* __restrict__ flags) {
    int bc = blockIdx.x;                         // b*C + c
    const float* sc = x + (size_t)bc * Nn * Nn + 1;  // x[b,c,0,1:]
    __shared__ float s_sc[Ss];
    for (int s = threadIdx.x; s < Ss; s += blockDim.x) s_sc[s] = sc[s];
    __syncthreads();
    for (int s = threadIdx.x; s < Ss; s += blockDim.x) {
        float v = s_sc[s];
        int rank = 0;
        for (int t = 0; t < Ss; ++t) {
            float u = s_sc[t];
            rank += (u > v) || (u == v && t < s);
        }
        bool sel = rank < PATCHNUM;              // lax.top_k: ties -> lower index first
        flags[(size_t)bc * Ss + s] = sel ? 1 : 0;
        nscore[(size_t)bc * Ss + s] = sel ? v : v * 0.7f;
    }
}

// ---------------- Kernel 2: per b: binary mask, anchor, rank-1 GCN -> struct[anchor] ----------------
__global__ __launch_bounds__(256) void k2_struct(const float* __restrict__ nscore,
                                                 const float* __restrict__ w1,
                                                 const float* __restrict__ w2,
                                                 float* __restrict__ structA) {
    int b = blockIdx.x;
    int tid = threadIdx.x;
    __shared__ float s_m[Ss];
    __shared__ float s_pw[Ss];
    __shared__ float red[256];
    __shared__ int   redi[256];
    __shared__ float s_v1[K1];

    const float* ns = nscore + (size_t)b * Cc * Ss;
    float lsum = 0.f;
    for (int s = tid; s < Ss; s += 256) {
        float m = 0.f;
        for (int c = 0; c < Cc; ++c) m += ns[c * Ss + s];
        s_m[s] = m;
        s_pw[s] = m / 12.0f;                     // pw = mean over C
        lsum += m;
    }
    // mean of m over S
    red[tid] = lsum; __syncthreads();
    for (int off = 128; off > 0; off >>= 1) {
        if (tid < off) red[tid] += red[tid + off];
        __syncthreads();
    }
    float meanm = red[0] / 784.0f;
    __syncthreads();

    // anchor = argmax_s ( (m>mean) ? pw : 0 ), first max wins
    float bestv = -INFINITY; int besti = Ss;
    for (int s = tid; s < Ss; s += 256) {
        float z = (s_m[s] > meanm) ? s_pw[s] : 0.0f;
        if (z > bestv) { bestv = z; besti = s; }
    }
    red[tid] = bestv; redi[tid] = besti; __syncthreads();
    for (int off = 128; off > 0; off >>= 1) {
        if (tid < off) {
            if (red[tid + off] > red[tid] ||
                (red[tid + off] == red[tid] && redi[tid + off] < redi[tid])) {
                red[tid] = red[tid + off]; redi[tid] = redi[tid + off];
            }
        }
        __syncthreads();
    }
    int anchor = redi[0];
    __syncthreads();

    // A = sum pw*dist, G = sum pw*ang, P2p = sum_{pw>0} pw^2, P2n = sum_{pw<0} pw^2
    int ai = anchor / Hh, aj = anchor % Hh;
    float lA = 0.f, lG = 0.f, lp = 0.f, ln2 = 0.f;
    const float PI_F = 3.14159265358979323846f;
    for (int s = tid; s < Ss; s += 256) {
        float pw = s_pw[s];
        int i = s / Hh, j = s % Hh;
        float ri = (float)(i - ai) / 28.0f;
        float rj = (float)(j - aj) / 28.0f;
        float dist = sqrtf(ri * ri + rj * rj);
        float ang = (atan2f(rj, ri) / PI_F + 1.0f) * 0.5f;
        lA += pw * dist;
        lG += pw * ang;
        if (pw > 0.f) lp += pw * pw;
        else if (pw < 0.f) ln2 += pw * pw;
    }
    float A, G, P2p, P2n;
    red[tid] = lA; __syncthreads();
    for (int off = 128; off > 0; off >>= 1) { if (tid < off) red[tid] += red[tid + off]; __syncthreads(); }
    A = red[0]; __syncthreads();
    red[tid] = lG; __syncthreads();
    for (int off = 128; off > 0; off >>= 1) { if (tid < off) red[tid] += red[tid + off]; __syncthreads(); }
    G = red[0]; __syncthreads();
    red[tid] = lp; __syncthreads();
    for (int off = 128; off > 0; off >>= 1) { if (tid < off) red[tid] += red[tid + off]; __syncthreads(); }
    P2p = red[0]; __syncthreads();
    red[tid] = ln2; __syncthreads();
    for (int off = 128; off > 0; off >>= 1) { if (tid < off) red[tid] += red[tid + off]; __syncthreads(); }
    P2n = red[0]; __syncthreads();

    // v1[k] = A*w1[0,k] + G*w1[1,k]
    for (int k = tid; k < K1; k += 256) s_v1[k] = A * w1[k] + G * w1[K1 + k];
    __syncthreads();

    float pwA = s_pw[anchor];
    for (int k2 = tid; k2 < Dd; k2 += 256) {
        float rp = 0.f, rn = 0.f;
        for (int k = 0; k < K1; ++k) {
            float v = s_v1[k];
            float w = w2[k * Dd + k2];
            rp += fmaxf(v, 0.f) * w;
            rn += fmaxf(-v, 0.f) * w;
        }
        float o2 = pwA * (P2p * rp - P2n * rn);
        structA[b * Dd + k2] = (o2 > 0.f) ? o2 : 0.2f * o2;   // leaky relu 0.2
    }
}

// ---------------- Kernel 3: per b: count -> 3x3 conv -> stable top-select_num positions ----------------
__global__ __launch_bounds__(256) void k3_count(const unsigned char* __restrict__ flags,
                                                int* __restrict__ selpos, int select_num) {
    int b = blockIdx.x;
    int tid = threadIdx.x;
    __shared__ int s_cnt[Ss];
    __shared__ int s_cc[Ss];
    for (int s = tid; s < Ss; s += 256) {
        int c0 = 0;
        for (int c = 0; c < Cc; ++c) c0 += flags[((size_t)b * Cc + c) * Ss + s];
        s_cnt[s] = c0;
    }
    __syncthreads();
    for (int s = tid; s < Ss; s += 256) {
        int i = s / Hh, j = s % Hh;
        int acc = 0;
        for (int di = -1; di <= 1; ++di)
            for (int dj = -1; dj <= 1; ++dj) {
                int ii = i + di, jj = j + dj;
                if (ii >= 0 && ii < Hh && jj >= 0 && jj < Hh)
                    acc += ((di == 0) ? 2 : 1) * ((dj == 0) ? 2 : 1) * s_cnt[ii * Hh + jj];
            }
        s_cc[s] = acc;
    }
    __syncthreads();
    // stable descending sort rank; keep first select_num positions (order matters)
    for (int s = tid; s < Ss; s += 256) {
        int v = s_cc[s];
        int rank = 0;
        for (int t = 0; t < Ss; ++t) {
            int u = s_cc[t];
            rank += (u > v) || (u == v && t < s);
        }
        if (rank < select_num) selpos[b * select_num + rank] = s + 1;
    }
}

// ---------------- Kernel 4a: out_hs = hidden_states, row 0 += struct[anchor] ----------------
__global__ __launch_bounds__(256) void k4a_copy(const float* __restrict__ hs,
                                                const float* __restrict__ structA,
                                                float* __restrict__ out) {
    size_t v = (size_t)blockIdx.x * blockDim.x + threadIdx.x;
    size_t total = (size_t)Bz * Nn * Dd / 4;
    if (v >= total) return;
    float4 val = ((const float4*)hs)[v];
    size_t fidx = v * 4;
    int b = (int)(fidx / ((size_t)Nn * Dd));
    int r = (int)(fidx % ((size_t)Nn * Dd));
    if (r < Dd) {
        float4 st = ((const float4*)structA)[(b * Dd + r) / 4];
        val.x += st.x; val.y += st.y; val.z += st.z; val.w += st.w;
    }
    ((float4*)out)[v] = val;
}

// ---------------- Kernel 4b: gather selected = hidden_states[b, selpos, :] ----------------
__global__ __launch_bounds__(256) void k4b_gather(const float* __restrict__ hs,
                                                  const int* __restrict__ selpos,
                                                  float* __restrict__ out, int select_num) {
    int v = blockIdx.x * blockDim.x + threadIdx.x;
    int total = Bz * select_num * Dd / 4;
    if (v >= total) return;
    int fidx = v * 4;
    int b = fidx / (select_num * Dd);
    int r = fidx % (select_num * Dd);
    int p = r / Dd;
    int d = r % Dd;
    int row = selpos[b * select_num + p];
    float4 val = *(const float4*)(hs + ((size_t)b * Nn + row) * Dd + d);
    ((float4*)out)[v] = val;
}

extern "C" void kernel_launch(void* const* d_in, const int* in_sizes, int n_in,
                              void* d_out, int out_size, void* d_ws, size_t ws_size,
                              hipStream_t stream) {
    const float* hs = (const float*)d_in[0];
    const float* x  = (const float*)d_in[1];
    const float* w1 = (const float*)d_in[2];
    const float* w2 = (const float*)d_in[3];
    float* out = (float*)d_out;

    const int hsN = Bz * Nn * Dd;                       // 4,823,040
    int select_num = (out_size - hsN) / (Bz * Dd);      // = 42

    // workspace carve (bytes)
    char* ws = (char*)d_ws;
    float* nscore = (float*)ws;                                   // B*C*S floats = 301056 B
    unsigned char* flags = (unsigned char*)(ws + 301056);         // B*C*S bytes  = 75264 B
    float* structA = (float*)(ws + 376320);                       // B*D floats   = 24576 B
    int* selpos = (int*)(ws + 400896);                            // B*select_num ints

    k1_score<<<Bz * Cc, 256, 0, stream>>>(x, nscore, flags);
    k2_struct<<<Bz, 256, 0, stream>>>(nscore, w1, w2, structA);
    k3_count<<<Bz, 256, 0, stream>>>(flags, selpos, select_num);

    int blocks4a = (hsN / 4 + 255) / 256;
    k4a_copy<<<blocks4a, 256, 0, stream>>>(hs, structA, out);

    int selTotal = Bz * select_num * Dd / 4;
    int blocks4b = (selTotal + 255) / 256;
    k4b_gather<<<blocks4b, 256, 0, stream>>>(hs, selpos, out + hsN, select_num);
}

// Round 2
// 160.562 us; speedup vs baseline: 1.5237x; 1.5237x over previous
//
#include <hip/hip_runtime.h>
#include <math.h>

#define Bz 8
#define Cc 12
#define Ss 784
#define Nn 785
#define Dd 768
#define Hh 28
#define K1 512
#define PATCHNUM 84

// ---------------- Kernel 1: per (b,c): top-84 select, new_score, flags ----------------
// grid (Bz*Cc, 2); each block handles 2 of the 4 value-strips per thread.
__global__ __launch_bounds__(256) void k1_score(const float* __restrict__ x,
                                                float* __restrict__ nscore,
                                                unsigned char* __restrict__ flags) {
    int bc = blockIdx.x;
    int half = blockIdx.y;                        // 0 or 1
    int tid = threadIdx.x;
    const float* sc = x + (size_t)bc * Nn * Nn + 1;   // x[b,c,0,1:]
    __shared__ float s_sc[Ss];
    for (int s = tid; s < Ss; s += 256) s_sc[s] = sc[s];
    __syncthreads();

    float v[2]; int sidx[2]; int rank[2];
#pragma unroll
    for (int q = 0; q < 2; ++q) {
        int s = tid + 256 * (2 * half + q);
        sidx[q] = s;
        v[q] = (s < Ss) ? s_sc[s] : 0.f;
        rank[q] = 0;
    }
    const float4* s4 = (const float4*)s_sc;
    for (int chunk = 0; chunk < Ss / 16; ++chunk) {   // 49 chunks of 16
        float4 c0 = s4[chunk * 4 + 0];
        float4 c1 = s4[chunk * 4 + 1];
        float4 c2 = s4[chunk * 4 + 2];
        float4 c3 = s4[chunk * 4 + 3];
        float c[16] = {c0.x, c0.y, c0.z, c0.w, c1.x, c1.y, c1.z, c1.w,
                       c2.x, c2.y, c2.z, c2.w, c3.x, c3.y, c3.z, c3.w};
#pragma unroll
        for (int u = 0; u < 16; ++u) {
            int t = chunk * 16 + u;
#pragma unroll
            for (int q = 0; q < 2; ++q)
                rank[q] += (c[u] > v[q]) || (c[u] == v[q] && t < sidx[q]);
        }
    }
#pragma unroll
    for (int q = 0; q < 2; ++q) {
        int s = sidx[q];
        if (s < Ss) {
            bool sel = rank[q] < PATCHNUM;         // lax.top_k tie-break: lower index
            flags[(size_t)bc * Ss + s] = sel ? 1 : 0;
            nscore[(size_t)bc * Ss + s] = sel ? v[q] : v[q] * 0.7f;
        }
    }
}

// ---------------- Kernel 2a: per b: mask, anchor, reductions, v1 -> ws ----------------
__global__ __launch_bounds__(256) void k2a_stats(const float* __restrict__ nscore,
                                                 const float* __restrict__ w1,
                                                 float* __restrict__ v1out,   // [Bz][K1]
                                                 float* __restrict__ cscal) { // [Bz][2] cp,cn
    int b = blockIdx.x;
    int tid = threadIdx.x;
    __shared__ float s_m[Ss];
    __shared__ float s_pw[Ss];
    __shared__ float red[256];
    __shared__ int   redi[256];

    const float* ns = nscore + (size_t)b * Cc * Ss;
    float lsum = 0.f;
    for (int s = tid; s < Ss; s += 256) {
        float m = 0.f;
        for (int c = 0; c < Cc; ++c) m += ns[c * Ss + s];
        s_m[s] = m;
        s_pw[s] = m / 12.0f;
        lsum += m;
    }
    red[tid] = lsum; __syncthreads();
    for (int off = 128; off > 0; off >>= 1) {
        if (tid < off) red[tid] += red[tid + off];
        __syncthreads();
    }
    float meanm = red[0] / 784.0f;
    __syncthreads();

    // anchor = argmax_s ((m>mean) ? pw : 0), first max wins
    float bestv = -INFINITY; int besti = Ss;
    for (int s = tid; s < Ss; s += 256) {
        float z = (s_m[s] > meanm) ? s_pw[s] : 0.0f;
        if (z > bestv) { bestv = z; besti = s; }
    }
    red[tid] = bestv; redi[tid] = besti; __syncthreads();
    for (int off = 128; off > 0; off >>= 1) {
        if (tid < off) {
            if (red[tid + off] > red[tid] ||
                (red[tid + off] == red[tid] && redi[tid + off] < redi[tid])) {
                red[tid] = red[tid + off]; redi[tid] = redi[tid + off];
            }
        }
        __syncthreads();
    }
    int anchor = redi[0];
    __syncthreads();

    int ai = anchor / Hh, aj = anchor % Hh;
    float lA = 0.f, lG = 0.f, lp = 0.f, ln2 = 0.f;
    const float PI_F = 3.14159265358979323846f;
    for (int s = tid; s < Ss; s += 256) {
        float pw = s_pw[s];
        int i = s / Hh, j = s % Hh;
        float ri = (float)(i - ai) / 28.0f;
        float rj = (float)(j - aj) / 28.0f;
        float dist = sqrtf(ri * ri + rj * rj);
        float ang = (atan2f(rj, ri) / PI_F + 1.0f) * 0.5f;
        lA += pw * dist;
        lG += pw * ang;
        if (pw > 0.f) lp += pw * pw;
        else if (pw < 0.f) ln2 += pw * pw;
    }
    float A, G, P2p, P2n;
    red[tid] = lA; __syncthreads();
    for (int off = 128; off > 0; off >>= 1) { if (tid < off) red[tid] += red[tid + off]; __syncthreads(); }
    A = red[0]; __syncthreads();
    red[tid] = lG; __syncthreads();
    for (int off = 128; off > 0; off >>= 1) { if (tid < off) red[tid] += red[tid + off]; __syncthreads(); }
    G = red[0]; __syncthreads();
    red[tid] = lp; __syncthreads();
    for (int off = 128; off > 0; off >>= 1) { if (tid < off) red[tid] += red[tid + off]; __syncthreads(); }
    P2p = red[0]; __syncthreads();
    red[tid] = ln2; __syncthreads();
    for (int off = 128; off > 0; off >>= 1) { if (tid < off) red[tid] += red[tid + off]; __syncthreads(); }
    P2n = red[0]; __syncthreads();

    for (int k = tid; k < K1; k += 256)
        v1out[b * K1 + k] = A * w1[k] + G * w1[K1 + k];
    if (tid == 0) {
        float pwA = s_pw[anchor];
        cscal[b * 2 + 0] = pwA * P2p;
        cscal[b * 2 + 1] = pwA * P2n;
    }
}

// ---------------- Kernel 2b: rank-1 matvec vs W2; grid (Bz*3), 256 cols each ----------------
__global__ __launch_bounds__(256) void k2b_matvec(const float* __restrict__ v1in,
                                                  const float* __restrict__ cscal,
                                                  const float* __restrict__ w2,
                                                  float* __restrict__ structA) {
    int blk = blockIdx.x;
    int b = blk / 3;
    int col = (blk % 3) * 256 + threadIdx.x;      // 0..767
    __shared__ float s_vp[K1];
    __shared__ float s_vn[K1];
    for (int k = threadIdx.x; k < K1; k += 256) {
        float v = v1in[b * K1 + k];
        s_vp[k] = fmaxf(v, 0.f);
        s_vn[k] = fmaxf(-v, 0.f);
    }
    __syncthreads();
    float cp = cscal[b * 2 + 0], cn = cscal[b * 2 + 1];
    float rp = 0.f, rn = 0.f;
#pragma unroll 4
    for (int k = 0; k < K1; ++k) {
        float w = w2[k * Dd + col];
        rp += s_vp[k] * w;
        rn += s_vn[k] * w;
    }
    float o2 = cp * rp - cn * rn;
    structA[b * Dd + col] = (o2 > 0.f) ? o2 : 0.2f * o2;
}

// ---------------- Kernel 3: count -> 3x3 conv -> stable rank; grid (Bz, 4) ----------------
__global__ __launch_bounds__(256) void k3_count(const unsigned char* __restrict__ flags,
                                                int* __restrict__ selpos, int select_num) {
    int b = blockIdx.x;
    int quarter = blockIdx.y;                     // 0..3
    int tid = threadIdx.x;
    __shared__ int s_cnt[Ss];
    __shared__ int s_cc[Ss];
    for (int s = tid; s < Ss; s += 256) {
        int c0 = 0;
        for (int c = 0; c < Cc; ++c) c0 += flags[((size_t)b * Cc + c) * Ss + s];
        s_cnt[s] = c0;
    }
    __syncthreads();
    for (int s = tid; s < Ss; s += 256) {
        int i = s / Hh, j = s % Hh;
        int acc = 0;
        for (int di = -1; di <= 1; ++di)
            for (int dj = -1; dj <= 1; ++dj) {
                int ii = i + di, jj = j + dj;
                if (ii >= 0 && ii < Hh && jj >= 0 && jj < Hh)
                    acc += ((di == 0) ? 2 : 1) * ((dj == 0) ? 2 : 1) * s_cnt[ii * Hh + jj];
            }
        s_cc[s] = acc;
    }
    __syncthreads();
    int s = tid + 256 * quarter;
    int v = 0, rank = 0;
    bool valid = (s < Ss);
    if (valid) v = s_cc[s];
    const int4* s4 = (const int4*)s_cc;
    for (int chunk = 0; chunk < Ss / 16; ++chunk) {
        int4 c0 = s4[chunk * 4 + 0];
        int4 c1 = s4[chunk * 4 + 1];
        int4 c2 = s4[chunk * 4 + 2];
        int4 c3 = s4[chunk * 4 + 3];
        int c[16] = {c0.x, c0.y, c0.z, c0.w, c1.x, c1.y, c1.z, c1.w,
                     c2.x, c2.y, c2.z, c2.w, c3.x, c3.y, c3.z, c3.w};
#pragma unroll
        for (int u = 0; u < 16; ++u) {
            int t = chunk * 16 + u;
            rank += (c[u] > v) || (c[u] == v && t < s);
        }
    }
    if (valid && rank < select_num)
        selpos[b * select_num + rank] = s + 1;    // +1: patch_idx offset
}

// ---------------- Kernel 4a: out_hs = hidden_states, row 0 += struct ----------------
__global__ __launch_bounds__(256) void k4a_copy(const float* __restrict__ hs,
                                                const float* __restrict__ structA,
                                                float* __restrict__ out) {
    size_t v = (size_t)blockIdx.x * blockDim.x + threadIdx.x;
    size_t total = (size_t)Bz * Nn * Dd / 4;
    if (v >= total) return;
    float4 val = ((const float4*)hs)[v];
    size_t fidx = v * 4;
    int b = (int)(fidx / ((size_t)Nn * Dd));
    int r = (int)(fidx % ((size_t)Nn * Dd));
    if (r < Dd) {
        float4 st = ((const float4*)structA)[(b * Dd + r) / 4];
        val.x += st.x; val.y += st.y; val.z += st.z; val.w += st.w;
    }
    ((float4*)out)[v] = val;
}

// ---------------- Kernel 4b: gather selected rows ----------------
__global__ __launch_bounds__(256) void k4b_gather(const float* __restrict__ hs,
                                                  const int* __restrict__ selpos,
                                                  float* __restrict__ out, int select_num) {
    int v = blockIdx.x * blockDim.x + threadIdx.x;
    int total = Bz * select_num * Dd / 4;
    if (v >= total) return;
    int fidx = v * 4;
    int b = fidx / (select_num * Dd);
    int r = fidx % (select_num * Dd);
    int p = r / Dd;
    int d = r % Dd;
    int row = selpos[b * select_num + p];
    float4 val = *(const float4*)(hs + ((size_t)b * Nn + row) * Dd + d);
    ((float4*)out)[v] = val;
}

extern "C" void kernel_launch(void* const* d_in, const int* in_sizes, int n_in,
                              void* d_out, int out_size, void* d_ws, size_t ws_size,
                              hipStream_t stream) {
    const float* hs = (const float*)d_in[0];
    const float* x  = (const float*)d_in[1];
    const float* w1 = (const float*)d_in[2];
    const float* w2 = (const float*)d_in[3];
    float* out = (float*)d_out;

    const int hsN = Bz * Nn * Dd;                       // 4,823,040
    int select_num = (out_size - hsN) / (Bz * Dd);      // = 42

    // workspace carve (bytes)
    char* ws = (char*)d_ws;
    float* nscore = (float*)ws;                                   // 96*784*4 = 301056 B
    unsigned char* flags = (unsigned char*)(ws + 301056);         // 96*784   =  75264 B
    float* structA = (float*)(ws + 376320);                       // 8*768*4  =  24576 B
    int* selpos = (int*)(ws + 400896);                            // 8*42*4   =   1344 B
    float* v1buf = (float*)(ws + 402432);                         // 8*512*4  =  16384 B
    float* cscal = (float*)(ws + 418816);                         // 8*2*4    =     64 B

    k1_score<<<dim3(Bz * Cc, 2), 256, 0, stream>>>(x, nscore, flags);
    k2a_stats<<<Bz, 256, 0, stream>>>(nscore, w1, v1buf, cscal);
    k2b_matvec<<<Bz * 3, 256, 0, stream>>>(v1buf, cscal, w2, structA);
    k3_count<<<dim3(Bz, 4), 256, 0, stream>>>(flags, selpos, select_num);

    int blocks4a = (hsN / 4 + 255) / 256;
    k4a_copy<<<blocks4a, 256, 0, stream>>>(hs, structA, out);

    int selTotal = Bz * select_num * Dd / 4;
    int blocks4b = (selTotal + 255) / 256;
    k4b_gather<<<blocks4b, 256, 0, stream>>>(hs, selpos, out + hsN, select_num);
}

// Round 3
// 71.996 us; speedup vs baseline: 3.3980x; 2.2302x over previous
//
#include <hip/hip_runtime.h>
#include <math.h>

#define Bz 8
#define Cc 12
#define Ss 784
#define Nn 785
#define Dd 768
#define Hh 28
#define K1 512
#define PATCHNUM 84

// ---------------- Kernel A: per (b,c): top-84 select, new_score, flags ----------------
// grid (Bz*Cc, 4); 1 value per thread.
__global__ __launch_bounds__(256) void kA_score(const float* __restrict__ x,
                                                float* __restrict__ nscore,
                                                unsigned char* __restrict__ flags) {
    int bc = blockIdx.x;
    int quarter = blockIdx.y;                     // 0..3
    int tid = threadIdx.x;
    const float* sc = x + (size_t)bc * Nn * Nn + 1;   // x[b,c,0,1:]
    __shared__ float s_sc[Ss];
    for (int s = tid; s < Ss; s += 256) s_sc[s] = sc[s];
    __syncthreads();

    int s = tid + 256 * quarter;
    bool valid = (s < Ss);
    float v = valid ? s_sc[s] : 0.f;
    int rank = 0;
    const float4* s4 = (const float4*)s_sc;
    for (int chunk = 0; chunk < Ss / 16; ++chunk) {   // 49 chunks of 16
        float4 c0 = s4[chunk * 4 + 0];
        float4 c1 = s4[chunk * 4 + 1];
        float4 c2 = s4[chunk * 4 + 2];
        float4 c3 = s4[chunk * 4 + 3];
        float c[16] = {c0.x, c0.y, c0.z, c0.w, c1.x, c1.y, c1.z, c1.w,
                       c2.x, c2.y, c2.z, c2.w, c3.x, c3.y, c3.z, c3.w};
#pragma unroll
        for (int u = 0; u < 16; ++u) {
            int t = chunk * 16 + u;
            rank += (c[u] > v) || (c[u] == v && t < s);
        }
    }
    if (valid) {
        bool sel = rank < PATCHNUM;               // lax.top_k tie-break: lower index
        flags[(size_t)bc * Ss + s] = sel ? 1 : 0;
        nscore[(size_t)bc * Ss + s] = sel ? v : v * 0.7f;
    }
}

// ---------------- Kernel B: per b: mask, anchor, reductions -> g[b,k] ----------------
// g[b,k] = cp*relu(v1_k) - cn*relu(-v1_k), so o2[b,:] = g[b,:] @ W2
__global__ __launch_bounds__(256) void kB_stats(const float* __restrict__ nscore,
                                                const float* __restrict__ w1,
                                                float* __restrict__ g) {    // [Bz][K1]
    int b = blockIdx.x;
    int tid = threadIdx.x;
    __shared__ float s_m[Ss];
    __shared__ float s_pw[Ss];
    __shared__ float red[256];
    __shared__ int   redi[256];

    const float* ns = nscore + (size_t)b * Cc * Ss;
    float lsum = 0.f;
    for (int s = tid; s < Ss; s += 256) {
        float m = 0.f;
        for (int c = 0; c < Cc; ++c) m += ns[c * Ss + s];
        s_m[s] = m;
        s_pw[s] = m / 12.0f;
        lsum += m;
    }
    red[tid] = lsum; __syncthreads();
    for (int off = 128; off > 0; off >>= 1) {
        if (tid < off) red[tid] += red[tid + off];
        __syncthreads();
    }
    float meanm = red[0] / 784.0f;
    __syncthreads();

    // anchor = argmax_s ((m>mean) ? pw : 0), first max wins
    float bestv = -INFINITY; int besti = Ss;
    for (int s = tid; s < Ss; s += 256) {
        float z = (s_m[s] > meanm) ? s_pw[s] : 0.0f;
        if (z > bestv) { bestv = z; besti = s; }
    }
    red[tid] = bestv; redi[tid] = besti; __syncthreads();
    for (int off = 128; off > 0; off >>= 1) {
        if (tid < off) {
            if (red[tid + off] > red[tid] ||
                (red[tid + off] == red[tid] && redi[tid + off] < redi[tid])) {
                red[tid] = red[tid + off]; redi[tid] = redi[tid + off];
            }
        }
        __syncthreads();
    }
    int anchor = redi[0];
    __syncthreads();

    int ai = anchor / Hh, aj = anchor % Hh;
    float lA = 0.f, lG = 0.f, lp = 0.f, ln2 = 0.f;
    const float PI_F = 3.14159265358979323846f;
    for (int s = tid; s < Ss; s += 256) {
        float pw = s_pw[s];
        int i = s / Hh, j = s % Hh;
        float ri = (float)(i - ai) / 28.0f;
        float rj = (float)(j - aj) / 28.0f;
        float dist = sqrtf(ri * ri + rj * rj);
        float ang = (atan2f(rj, ri) / PI_F + 1.0f) * 0.5f;
        lA += pw * dist;
        lG += pw * ang;
        if (pw > 0.f) lp += pw * pw;
        else if (pw < 0.f) ln2 += pw * pw;
    }
    float A, G, P2p, P2n;
    red[tid] = lA; __syncthreads();
    for (int off = 128; off > 0; off >>= 1) { if (tid < off) red[tid] += red[tid + off]; __syncthreads(); }
    A = red[0]; __syncthreads();
    red[tid] = lG; __syncthreads();
    for (int off = 128; off > 0; off >>= 1) { if (tid < off) red[tid] += red[tid + off]; __syncthreads(); }
    G = red[0]; __syncthreads();
    red[tid] = lp; __syncthreads();
    for (int off = 128; off > 0; off >>= 1) { if (tid < off) red[tid] += red[tid + off]; __syncthreads(); }
    P2p = red[0]; __syncthreads();
    red[tid] = ln2; __syncthreads();
    for (int off = 128; off > 0; off >>= 1) { if (tid < off) red[tid] += red[tid + off]; __syncthreads(); }
    P2n = red[0]; __syncthreads();

    float pwA = s_pw[anchor];
    float cp = pwA * P2p, cn = pwA * P2n;
    for (int k = tid; k < K1; k += 256) {
        float v = A * w1[k] + G * w1[K1 + k];
        g[b * K1 + k] = cp * fmaxf(v, 0.f) - cn * fmaxf(-v, 0.f);
    }
}

// ---------------- Kernel C: partial matvec; grid (3 colblk, 8 kblk) ----------------
// partial[kb][b][col] = sum_{k in kb} g[b,k] * w2[k,col]
__global__ __launch_bounds__(256) void kC_matvec(const float* __restrict__ g,
                                                 const float* __restrict__ w2,
                                                 float* __restrict__ pbuf) {
    int colblk = blockIdx.x;          // 0..2
    int kb = blockIdx.y;              // 0..7
    int tid = threadIdx.x;
    int col = colblk * 256 + tid;
    __shared__ float s_g[Bz][64];
    if (tid < 128) {
        // load 8*64=512 floats with 128 threads, 4 each
        for (int u = tid; u < Bz * 64; u += 128) {
            int b = u / 64, kk = u % 64;
            s_g[b][kk] = g[b * K1 + kb * 64 + kk];
        }
    }
    __syncthreads();
    float acc[Bz];
#pragma unroll
    for (int b = 0; b < Bz; ++b) acc[b] = 0.f;
    const float* w2p = w2 + (size_t)(kb * 64) * Dd + col;
#pragma unroll 8
    for (int kk = 0; kk < 64; ++kk) {
        float w = w2p[kk * Dd];
#pragma unroll
        for (int b = 0; b < Bz; ++b) acc[b] += s_g[b][kk] * w;
    }
#pragma unroll
    for (int b = 0; b < Bz; ++b)
        pbuf[((size_t)kb * Bz + b) * Dd + col] = acc[b];
}

// ---------------- Kernel D: count -> 3x3 conv -> stable rank; grid (Bz, 4) ----------------
__global__ __launch_bounds__(256) void kD_count(const unsigned char* __restrict__ flags,
                                                int* __restrict__ selpos, int select_num) {
    int b = blockIdx.x;
    int quarter = blockIdx.y;                     // 0..3
    int tid = threadIdx.x;
    __shared__ int s_cnt[Ss];
    __shared__ int s_cc[Ss];
    for (int s = tid; s < Ss; s += 256) {
        int c0 = 0;
        for (int c = 0; c < Cc; ++c) c0 += flags[((size_t)b * Cc + c) * Ss + s];
        s_cnt[s] = c0;
    }
    __syncthreads();
    for (int s = tid; s < Ss; s += 256) {
        int i = s / Hh, j = s % Hh;
        int acc = 0;
        for (int di = -1; di <= 1; ++di)
            for (int dj = -1; dj <= 1; ++dj) {
                int ii = i + di, jj = j + dj;
                if (ii >= 0 && ii < Hh && jj >= 0 && jj < Hh)
                    acc += ((di == 0) ? 2 : 1) * ((dj == 0) ? 2 : 1) * s_cnt[ii * Hh + jj];
            }
        s_cc[s] = acc;
    }
    __syncthreads();
    int s = tid + 256 * quarter;
    int v = 0, rank = 0;
    bool valid = (s < Ss);
    if (valid) v = s_cc[s];
    const int4* s4 = (const int4*)s_cc;
    for (int chunk = 0; chunk < Ss / 16; ++chunk) {
        int4 c0 = s4[chunk * 4 + 0];
        int4 c1 = s4[chunk * 4 + 1];
        int4 c2 = s4[chunk * 4 + 2];
        int4 c3 = s4[chunk * 4 + 3];
        int c[16] = {c0.x, c0.y, c0.z, c0.w, c1.x, c1.y, c1.z, c1.w,
                     c2.x, c2.y, c2.z, c2.w, c3.x, c3.y, c3.z, c3.w};
#pragma unroll
        for (int u = 0; u < 16; ++u) {
            int t = chunk * 16 + u;
            rank += (c[u] > v) || (c[u] == v && t < s);
        }
    }
    if (valid && rank < select_num)
        selpos[b * select_num + rank] = s + 1;    // +1: patch_idx offset
}

// ---------------- Kernel E: fused output: copy + row0 (reduce partials, lrelu, add) + gather ----------------
__global__ __launch_bounds__(256) void kE_out(const float* __restrict__ hs,
                                              const float* __restrict__ pbuf,
                                              const int* __restrict__ selpos,
                                              float* __restrict__ out,
                                              int select_num, int blocksCopy) {
    int bid = blockIdx.x;
    if (bid < blocksCopy) {
        size_t v = (size_t)bid * 256 + threadIdx.x;
        size_t total = (size_t)Bz * Nn * Dd / 4;
        if (v >= total) return;
        float4 val = ((const float4*)hs)[v];
        size_t fidx = v * 4;
        int b = (int)(fidx / ((size_t)Nn * Dd));
        int r = (int)(fidx % ((size_t)Nn * Dd));
        if (r < Dd) {
            float4 o2 = make_float4(0.f, 0.f, 0.f, 0.f);
#pragma unroll
            for (int kb = 0; kb < 8; ++kb) {
                float4 p = *(const float4*)(pbuf + ((size_t)kb * Bz + b) * Dd + r);
                o2.x += p.x; o2.y += p.y; o2.z += p.z; o2.w += p.w;
            }
            val.x += (o2.x > 0.f) ? o2.x : 0.2f * o2.x;
            val.y += (o2.y > 0.f) ? o2.y : 0.2f * o2.y;
            val.z += (o2.z > 0.f) ? o2.z : 0.2f * o2.z;
            val.w += (o2.w > 0.f) ? o2.w : 0.2f * o2.w;
        }
        ((float4*)out)[v] = val;
    } else {
        int v = (bid - blocksCopy) * 256 + threadIdx.x;
        int total = Bz * select_num * Dd / 4;
        if (v >= total) return;
        int fidx = v * 4;
        int b = fidx / (select_num * Dd);
        int r = fidx % (select_num * Dd);
        int p = r / Dd;
        int d = r % Dd;
        int row = selpos[b * select_num + p];
        float4 val = *(const float4*)(hs + ((size_t)b * Nn + row) * Dd + d);
        ((float4*)(out + (size_t)Bz * Nn * Dd))[v] = val;
    }
}

extern "C" void kernel_launch(void* const* d_in, const int* in_sizes, int n_in,
                              void* d_out, int out_size, void* d_ws, size_t ws_size,
                              hipStream_t stream) {
    const float* hs = (const float*)d_in[0];
    const float* x  = (const float*)d_in[1];
    const float* w1 = (const float*)d_in[2];
    const float* w2 = (const float*)d_in[3];
    float* out = (float*)d_out;

    const int hsN = Bz * Nn * Dd;                       // 4,823,040
    int select_num = (out_size - hsN) / (Bz * Dd);      // = 42

    // workspace carve (bytes)
    char* ws = (char*)d_ws;
    float* nscore = (float*)ws;                                   // 96*784*4  = 301056 B
    unsigned char* flags = (unsigned char*)(ws + 301056);         // 96*784    =  75264 B
    float* g     = (float*)(ws + 376320);                         // 8*512*4   =  16384 B
    float* pbuf  = (float*)(ws + 392704);                         // 8*8*768*4 = 196608 B
    int* selpos  = (int*)(ws + 589312);                           // 8*42*4    =   1344 B

    kA_score<<<dim3(Bz * Cc, 4), 256, 0, stream>>>(x, nscore, flags);
    kB_stats<<<Bz, 256, 0, stream>>>(nscore, w1, g);
    kC_matvec<<<dim3(3, 8), 256, 0, stream>>>(g, w2, pbuf);
    kD_count<<<dim3(Bz, 4), 256, 0, stream>>>(flags, selpos, select_num);

    int blocksCopy = (hsN / 4 + 255) / 256;             // 4710
    int selTotal = Bz * select_num * Dd / 4;
    int blocksGather = (selTotal + 255) / 256;          // 63
    kE_out<<<blocksCopy + blocksGather, 256, 0, stream>>>(hs, pbuf, selpos, out,
                                                          select_num, blocksCopy);
}

// Round 4
// 54.462 us; speedup vs baseline: 4.4920x; 1.3220x over previous
//
#include <hip/hip_runtime.h>
#include <math.h>

#define Bz 8
#define Cc 12
#define Ss 784
#define Nn 785
#define Dd 768
#define Hh 28
#define K1 512
#define PATCHNUM 84

__device__ inline float waveSum(float v) {
#pragma unroll
    for (int off = 32; off > 0; off >>= 1) v += __shfl_xor(v, off);
    return v;
}

// ---------------- Kernel A: per (b,c): top-84 select, new_score, flags ----------------
// grid (Bz*Cc, 4); 1 value per thread.
__global__ __launch_bounds__(256) void kA_score(const float* __restrict__ x,
                                                float* __restrict__ nscore,
                                                unsigned char* __restrict__ flags) {
    int bc = blockIdx.x;
    int quarter = blockIdx.y;                     // 0..3
    int tid = threadIdx.x;
    const float* sc = x + (size_t)bc * Nn * Nn + 1;   // x[b,c,0,1:]
    __shared__ float s_sc[Ss];
    for (int s = tid; s < Ss; s += 256) s_sc[s] = sc[s];
    __syncthreads();

    int s = tid + 256 * quarter;
    bool valid = (s < Ss);
    float v = valid ? s_sc[s] : 0.f;
    int rank = 0;
    const float4* s4 = (const float4*)s_sc;
    for (int chunk = 0; chunk < Ss / 16; ++chunk) {   // 49 chunks of 16
        float4 c0 = s4[chunk * 4 + 0];
        float4 c1 = s4[chunk * 4 + 1];
        float4 c2 = s4[chunk * 4 + 2];
        float4 c3 = s4[chunk * 4 + 3];
        float c[16] = {c0.x, c0.y, c0.z, c0.w, c1.x, c1.y, c1.z, c1.w,
                       c2.x, c2.y, c2.z, c2.w, c3.x, c3.y, c3.z, c3.w};
#pragma unroll
        for (int u = 0; u < 16; ++u) {
            int t = chunk * 16 + u;
            rank += (c[u] > v) || (c[u] == v && t < s);
        }
    }
    if (valid) {
        bool sel = rank < PATCHNUM;               // lax.top_k tie-break: lower index
        flags[(size_t)bc * Ss + s] = sel ? 1 : 0;
        nscore[(size_t)bc * Ss + s] = sel ? v : v * 0.7f;
    }
}

// ---------------- Kernel Mid: fused stats+matvec (192 blocks) and count/rank (32 blocks) ----------------
// blocks [0,192): b = bid/24, kb = (bid%24)/3, colblk = bid%3
//   recompute per-b stats (redundant across 24 blocks) then partial matvec:
//   pbuf[kb][b][col] = sum_{k in kb-chunk} g[b,k]*w2[k,col],
//   g[b,k] = cp*relu(v1_k) - cn*relu(-v1_k), v1 = A*w1[0,:] + G*w1[1,:]
// blocks [192,224): count -> 3x3 conv -> stable rank -> selpos
__global__ __launch_bounds__(256) void kMid(const float* __restrict__ nscore,
                                            const unsigned char* __restrict__ flags,
                                            const float* __restrict__ w1,
                                            const float* __restrict__ w2,
                                            float* __restrict__ pbuf,
                                            int* __restrict__ selpos, int select_num) {
    int bid = blockIdx.x;
    int tid = threadIdx.x;
    int wid = tid >> 6, lane = tid & 63;

    if (bid < 192) {
        int b = bid / 24;
        int r = bid % 24;
        int kb = r / 3, colblk = r % 3;
        __shared__ float s_m[Ss];
        __shared__ float s_pw[Ss];
        __shared__ float s_g[64];
        __shared__ float s_w1[4];
        __shared__ float s_w4[4][4];
        __shared__ float s_av[4];
        __shared__ int   s_ai[4];

        const float* ns = nscore + (size_t)b * Cc * Ss;
        float lsum = 0.f;
        for (int s = tid; s < Ss; s += 256) {
            float m = 0.f;
#pragma unroll
            for (int c = 0; c < Cc; ++c) m += ns[c * Ss + s];
            s_m[s] = m;
            s_pw[s] = m / 12.0f;
            lsum += m;
        }
        lsum = waveSum(lsum);
        if (lane == 0) s_w1[wid] = lsum;
        __syncthreads();
        float meanm = (s_w1[0] + s_w1[1] + s_w1[2] + s_w1[3]) / 784.0f;

        // anchor = argmax_s ((m>mean) ? pw : 0), first max wins
        float bv = -INFINITY; int bi = Ss;
        for (int s = tid; s < Ss; s += 256) {
            float z = (s_m[s] > meanm) ? s_pw[s] : 0.0f;
            if (z > bv) { bv = z; bi = s; }
        }
#pragma unroll
        for (int off = 32; off > 0; off >>= 1) {
            float ov = __shfl_xor(bv, off);
            int   oi = __shfl_xor(bi, off);
            if (ov > bv || (ov == bv && oi < bi)) { bv = ov; bi = oi; }
        }
        if (lane == 0) { s_av[wid] = bv; s_ai[wid] = bi; }
        __syncthreads();
        float abv = s_av[0]; int anchor = s_ai[0];
#pragma unroll
        for (int w = 1; w < 4; ++w) {
            if (s_av[w] > abv || (s_av[w] == abv && s_ai[w] < anchor)) {
                abv = s_av[w]; anchor = s_ai[w];
            }
        }

        int ai = anchor / Hh, aj = anchor % Hh;
        float lA = 0.f, lG = 0.f, lp = 0.f, ln2 = 0.f;
        const float PI_F = 3.14159265358979323846f;
        for (int s = tid; s < Ss; s += 256) {
            float pw = s_pw[s];
            int i = s / Hh, j = s % Hh;
            float ri = (float)(i - ai) / 28.0f;
            float rj = (float)(j - aj) / 28.0f;
            float dist = sqrtf(ri * ri + rj * rj);
            float ang = (atan2f(rj, ri) / PI_F + 1.0f) * 0.5f;
            lA += pw * dist;
            lG += pw * ang;
            if (pw > 0.f) lp += pw * pw;
            else if (pw < 0.f) ln2 += pw * pw;
        }
        lA = waveSum(lA); lG = waveSum(lG); lp = waveSum(lp); ln2 = waveSum(ln2);
        if (lane == 0) {
            s_w4[wid][0] = lA; s_w4[wid][1] = lG; s_w4[wid][2] = lp; s_w4[wid][3] = ln2;
        }
        __syncthreads();
        float A   = s_w4[0][0] + s_w4[1][0] + s_w4[2][0] + s_w4[3][0];
        float G   = s_w4[0][1] + s_w4[1][1] + s_w4[2][1] + s_w4[3][1];
        float P2p = s_w4[0][2] + s_w4[1][2] + s_w4[2][2] + s_w4[3][2];
        float P2n = s_w4[0][3] + s_w4[1][3] + s_w4[2][3] + s_w4[3][3];
        float pwA = s_pw[anchor];
        float cp = pwA * P2p, cn = pwA * P2n;

        if (tid < 64) {
            int k = kb * 64 + tid;
            float v = A * w1[k] + G * w1[K1 + k];
            s_g[tid] = cp * fmaxf(v, 0.f) - cn * fmaxf(-v, 0.f);
        }
        __syncthreads();

        int col = colblk * 256 + tid;
        float acc = 0.f;
        const float* w2p = w2 + (size_t)(kb * 64) * Dd + col;
#pragma unroll 8
        for (int kk = 0; kk < 64; ++kk)
            acc += s_g[kk] * w2p[kk * Dd];
        pbuf[((size_t)kb * Bz + b) * Dd + col] = acc;
    } else {
        int u = bid - 192;
        int b = u / 4;
        int quarter = u % 4;
        __shared__ int s_cnt[Ss];
        __shared__ int s_cc[Ss];
        for (int s = tid; s < Ss; s += 256) {
            int c0 = 0;
#pragma unroll
            for (int c = 0; c < Cc; ++c) c0 += flags[((size_t)b * Cc + c) * Ss + s];
            s_cnt[s] = c0;
        }
        __syncthreads();
        for (int s = tid; s < Ss; s += 256) {
            int i = s / Hh, j = s % Hh;
            int acc = 0;
            for (int di = -1; di <= 1; ++di)
                for (int dj = -1; dj <= 1; ++dj) {
                    int ii = i + di, jj = j + dj;
                    if (ii >= 0 && ii < Hh && jj >= 0 && jj < Hh)
                        acc += ((di == 0) ? 2 : 1) * ((dj == 0) ? 2 : 1) * s_cnt[ii * Hh + jj];
                }
            s_cc[s] = acc;
        }
        __syncthreads();
        int s = tid + 256 * quarter;
        int v = 0, rank = 0;
        bool valid = (s < Ss);
        if (valid) v = s_cc[s];
        const int4* s4 = (const int4*)s_cc;
        for (int chunk = 0; chunk < Ss / 16; ++chunk) {
            int4 c0 = s4[chunk * 4 + 0];
            int4 c1 = s4[chunk * 4 + 1];
            int4 c2 = s4[chunk * 4 + 2];
            int4 c3 = s4[chunk * 4 + 3];
            int c[16] = {c0.x, c0.y, c0.z, c0.w, c1.x, c1.y, c1.z, c1.w,
                         c2.x, c2.y, c2.z, c2.w, c3.x, c3.y, c3.z, c3.w};
#pragma unroll
            for (int u2 = 0; u2 < 16; ++u2) {
                int t = chunk * 16 + u2;
                rank += (c[u2] > v) || (c[u2] == v && t < s);
            }
        }
        if (valid && rank < select_num)
            selpos[b * select_num + rank] = s + 1;    // +1: patch_idx offset
    }
}

// ---------------- Kernel E: fused output: copy + row0 (reduce partials, lrelu, add) + gather ----------------
__global__ __launch_bounds__(256) void kE_out(const float* __restrict__ hs,
                                              const float* __restrict__ pbuf,
                                              const int* __restrict__ selpos,
                                              float* __restrict__ out,
                                              int select_num, int blocksCopy) {
    int bid = blockIdx.x;
    if (bid < blocksCopy) {
        size_t v = (size_t)bid * 256 + threadIdx.x;
        size_t total = (size_t)Bz * Nn * Dd / 4;
        if (v >= total) return;
        float4 val = ((const float4*)hs)[v];
        size_t fidx = v * 4;
        int b = (int)(fidx / ((size_t)Nn * Dd));
        int r = (int)(fidx % ((size_t)Nn * Dd));
        if (r < Dd) {
            float4 o2 = make_float4(0.f, 0.f, 0.f, 0.f);
#pragma unroll
            for (int kb = 0; kb < 8; ++kb) {
                float4 p = *(const float4*)(pbuf + ((size_t)kb * Bz + b) * Dd + r);
                o2.x += p.x; o2.y += p.y; o2.z += p.z; o2.w += p.w;
            }
            val.x += (o2.x > 0.f) ? o2.x : 0.2f * o2.x;
            val.y += (o2.y > 0.f) ? o2.y : 0.2f * o2.y;
            val.z += (o2.z > 0.f) ? o2.z : 0.2f * o2.z;
            val.w += (o2.w > 0.f) ? o2.w : 0.2f * o2.w;
        }
        ((float4*)out)[v] = val;
    } else {
        int v = (bid - blocksCopy) * 256 + threadIdx.x;
        int total = Bz * select_num * Dd / 4;
        if (v >= total) return;
        int fidx = v * 4;
        int b = fidx / (select_num * Dd);
        int r = fidx % (select_num * Dd);
        int p = r / Dd;
        int d = r % Dd;
        int row = selpos[b * select_num + p];
        float4 val = *(const float4*)(hs + ((size_t)b * Nn + row) * Dd + d);
        ((float4*)(out + (size_t)Bz * Nn * Dd))[v] = val;
    }
}

extern "C" void kernel_launch(void* const* d_in, const int* in_sizes, int n_in,
                              void* d_out, int out_size, void* d_ws, size_t ws_size,
                              hipStream_t stream) {
    const float* hs = (const float*)d_in[0];
    const float* x  = (const float*)d_in[1];
    const float* w1 = (const float*)d_in[2];
    const float* w2 = (const float*)d_in[3];
    float* out = (float*)d_out;

    const int hsN = Bz * Nn * Dd;                       // 4,823,040
    int select_num = (out_size - hsN) / (Bz * Dd);      // = 42

    // workspace carve (bytes)
    char* ws = (char*)d_ws;
    float* nscore = (float*)ws;                                   // 96*784*4  = 301056 B
    unsigned char* flags = (unsigned char*)(ws + 301056);         // 96*784    =  75264 B
    float* pbuf  = (float*)(ws + 376320);                         // 8*8*768*4 = 196608 B
    int* selpos  = (int*)(ws + 572928);                           // 8*42*4    =   1344 B

    kA_score<<<dim3(Bz * Cc, 4), 256, 0, stream>>>(x, nscore, flags);
    kMid<<<224, 256, 0, stream>>>(nscore, flags, w1, w2, pbuf, selpos, select_num);

    int blocksCopy = (hsN / 4 + 255) / 256;             // 4710
    int selTotal = Bz * select_num * Dd / 4;
    int blocksGather = (selTotal + 255) / 256;          // 63
    kE_out<<<blocksCopy + blocksGather, 256, 0, stream>>>(hs, pbuf, selpos, out,
                                                          select_num, blocksCopy);
}